// Round 1
// baseline (1105.377 us; speedup 1.0000x reference)
//
#include <hip/hip_runtime.h>
#include <math.h>

// VGAE forward: 3x GCNConv + reparameterize.
// Pipeline: CSR build (count/scan/fill) -> GEMM1 -> agg1(+b1,relu) ->
//           GEMM2 (W_mu|W_lv fused) -> agg2 (direct into d_out mu/lv) -> z.

__global__ __launch_bounds__(256) void k_count(const int* __restrict__ coli,
                                               int* __restrict__ cnt, int E) {
    int e = blockIdx.x * 256 + threadIdx.x;
    if (e < E) atomicAdd(&cnt[coli[e]], 1);
}

// Single-block exclusive scan over cnt -> rowptr, cursor; also dis = rsqrt(deg).
__global__ __launch_bounds__(1024) void k_scan(const int* __restrict__ cnt,
                                               int* __restrict__ rowptr,
                                               int* __restrict__ cursor,
                                               float* __restrict__ dis,
                                               int N, int E) {
    __shared__ int part[1024];
    __shared__ int excl[1024];
    int tid = threadIdx.x;
    int chunk = (N + 1023) >> 10;
    int s = tid * chunk;
    int e = min(s + chunk, N);
    int sum = 0;
    for (int i = s; i < e; i++) sum += cnt[i];
    part[tid] = sum;
    __syncthreads();
    if (tid == 0) {
        int run = 0;
        for (int i = 0; i < 1024; i++) { excl[i] = run; run += part[i]; }
    }
    __syncthreads();
    int run = excl[tid];
    for (int i = s; i < e; i++) {
        rowptr[i] = run;
        cursor[i] = run;
        dis[i] = rsqrtf((float)(cnt[i] + 1));  // +1 self loop; deg >= 1 always
        run += cnt[i];
    }
    if (tid == 0) rowptr[N] = E;
}

__global__ __launch_bounds__(256) void k_fill(const int* __restrict__ rowi,
                                              const int* __restrict__ coli,
                                              int* __restrict__ cursor,
                                              int* __restrict__ srcs, int E) {
    int e = blockIdx.x * 256 + threadIdx.x;
    if (e < E) {
        int c = coli[e];
        int pos = atomicAdd(&cursor[c], 1);
        srcs[pos] = rowi[e];
    }
}

__device__ inline float4 f4fma(float s, float4 w, float4 a) {
    a.x = fmaf(s, w.x, a.x);
    a.y = fmaf(s, w.y, a.y);
    a.z = fmaf(s, w.z, a.z);
    a.w = fmaf(s, w.w, a.w);
    return a;
}

// Y[M,128] = X[M,128] @ W[128,128], where W cols [0,split) come from Wa
// (row stride split) and cols [split,128) from Wb (row stride 128-split).
// Block: 64 rows x 128 cols; thread: 8 rows x 4 cols.
__global__ __launch_bounds__(256) void k_gemm(const float* __restrict__ X,
                                              const float* __restrict__ Wa,
                                              const float* __restrict__ Wb,
                                              int split,
                                              float* __restrict__ Y, int M) {
    __shared__ float Ws[128][128];  // 64 KB
    int wbs = 128 - split;
    for (int i = threadIdx.x; i < 128 * 128; i += 256) {
        int k = i >> 7, j = i & 127;
        Ws[k][j] = (j < split) ? Wa[k * split + j] : Wb[k * wbs + (j - split)];
    }
    __syncthreads();

    int c4 = (threadIdx.x & 31) << 2;            // col base
    int r0 = blockIdx.x * 64 + (threadIdx.x >> 5) * 8;  // 8 rows per thread
    float4 acc[8];
#pragma unroll
    for (int r = 0; r < 8; r++) acc[r] = make_float4(0.f, 0.f, 0.f, 0.f);
    int rowidx[8];
#pragma unroll
    for (int r = 0; r < 8; r++) rowidx[r] = min(r0 + r, M - 1);  // clamp loads

    for (int k = 0; k < 128; k += 4) {
        float4 w0 = *(const float4*)&Ws[k + 0][c4];
        float4 w1 = *(const float4*)&Ws[k + 1][c4];
        float4 w2 = *(const float4*)&Ws[k + 2][c4];
        float4 w3 = *(const float4*)&Ws[k + 3][c4];
#pragma unroll
        for (int r = 0; r < 8; r++) {
            float4 xv = *(const float4*)&X[rowidx[r] * 128 + k];
            acc[r] = f4fma(xv.x, w0, acc[r]);
            acc[r] = f4fma(xv.y, w1, acc[r]);
            acc[r] = f4fma(xv.z, w2, acc[r]);
            acc[r] = f4fma(xv.w, w3, acc[r]);
        }
    }
#pragma unroll
    for (int r = 0; r < 8; r++) {
        int row = r0 + r;
        if (row < M) *(float4*)&Y[row * 128 + c4] = acc[r];
    }
}

// out[i] = bias + dis_i * ( sum_{e:col=i} dis[src_e]*F[src_e] + dis_i*F[i] )
// One wave per node, 2 cols per lane. split==out row stride (128 or 64).
__global__ __launch_bounds__(256) void k_agg(const float* __restrict__ F,
                                             const float* __restrict__ dis,
                                             const int* __restrict__ rowptr,
                                             const int* __restrict__ srcs,
                                             const float* __restrict__ ba,
                                             const float* __restrict__ bb,
                                             int split,
                                             float* __restrict__ outA,
                                             float* __restrict__ outB,
                                             int relu, int N) {
    int node = blockIdx.x * 4 + (threadIdx.x >> 6);
    if (node >= N) return;
    int lane = threadIdx.x & 63;
    int j = lane << 1;
    const float2* Fr = (const float2*)F;
    float di = dis[node];
    float2 sv = Fr[node * 64 + lane];
    float ax = di * sv.x;
    float ay = di * sv.y;
    int s = rowptr[node], e = rowptr[node + 1];
    for (int t = s; t < e; t++) {
        int sr = srcs[t];
        float w = dis[sr];
        float2 f = Fr[sr * 64 + lane];
        ax = fmaf(w, f.x, ax);
        ay = fmaf(w, f.y, ay);
    }
    ax *= di;
    ay *= di;
    float* op;
    int jj;
    float b0, b1v;
    if (j < split) { op = outA; jj = j; b0 = ba[jj]; b1v = ba[jj + 1]; }
    else           { op = outB; jj = j - split; b0 = bb[jj]; b1v = bb[jj + 1]; }
    float o0 = ax + b0, o1 = ay + b1v;
    if (relu) { o0 = fmaxf(o0, 0.f); o1 = fmaxf(o1, 0.f); }
    *(float2*)&op[node * split + jj] = make_float2(o0, o1);
}

__global__ __launch_bounds__(256) void k_final(const float* __restrict__ mu,
                                               const float* __restrict__ lv,
                                               const float* __restrict__ eps,
                                               float* __restrict__ z, int n) {
    int i = blockIdx.x * 256 + threadIdx.x;
    if (i < n) z[i] = fmaf(eps[i], expf(0.5f * lv[i]), mu[i]);
}

extern "C" void kernel_launch(void* const* d_in, const int* in_sizes, int n_in,
                              void* d_out, int out_size, void* d_ws, size_t ws_size,
                              hipStream_t stream) {
    const float* x   = (const float*)d_in[0];
    const int*   ei  = (const int*)d_in[1];
    const float* W1  = (const float*)d_in[2];
    const float* b1  = (const float*)d_in[3];
    const float* Wmu = (const float*)d_in[4];
    const float* bmu = (const float*)d_in[5];
    const float* Wlv = (const float*)d_in[6];
    const float* blv = (const float*)d_in[7];
    const float* eps = (const float*)d_in[8];

    int N = in_sizes[0] / 128;   // 100000
    int E = in_sizes[1] / 2;     // 1600000
    const int* rowi = ei;        // edge_index[0]
    const int* coli = ei + E;    // edge_index[1]

    char* ws = (char*)d_ws;
    size_t off = 0;
    auto alloc = [&](size_t bytes) -> void* {
        void* p = ws + off;
        off += (bytes + 255) & ~(size_t)255;
        return p;
    };
    float* bufA   = (float*)alloc((size_t)N * 128 * 4);  // h_pre, then hcat
    float* bufB   = (float*)alloc((size_t)N * 128 * 4);  // h
    float* dis    = (float*)alloc((size_t)N * 4);
    int*   cnt    = (int*)alloc((size_t)N * 4);
    int*   rowptr = (int*)alloc((size_t)(N + 1) * 4);
    int*   cursor = (int*)alloc((size_t)N * 4);
    int*   srcs   = (int*)alloc((size_t)E * 4);

    float* zo  = (float*)d_out;                 // [N,64]
    float* muo = zo + (size_t)N * 64;           // [N,64]
    float* lvo = zo + (size_t)N * 128;          // [N,64]

    hipMemsetAsync(cnt, 0, (size_t)N * 4, stream);
    k_count<<<(E + 255) / 256, 256, 0, stream>>>(coli, cnt, E);
    k_scan<<<1, 1024, 0, stream>>>(cnt, rowptr, cursor, dis, N, E);
    k_fill<<<(E + 255) / 256, 256, 0, stream>>>(rowi, coli, cursor, srcs, E);

    k_gemm<<<(N + 63) / 64, 256, 0, stream>>>(x, W1, W1, 128, bufA, N);
    k_agg<<<(N + 3) / 4, 256, 0, stream>>>(bufA, dis, rowptr, srcs,
                                           b1, b1, 128, bufB, bufB, 1, N);
    k_gemm<<<(N + 63) / 64, 256, 0, stream>>>(bufB, Wmu, Wlv, 64, bufA, N);
    k_agg<<<(N + 3) / 4, 256, 0, stream>>>(bufA, dis, rowptr, srcs,
                                           bmu, blv, 64, muo, lvo, 0, N);
    k_final<<<((N * 64) + 255) / 256, 256, 0, stream>>>(muo, lvo, eps, zo, N * 64);
}

// Round 2
// 836.728 us; speedup vs baseline: 1.3211x; 1.3211x over previous
//
#include <hip/hip_runtime.h>
#include <math.h>

// VGAE forward: 3x GCNConv + reparameterize.
// Pipeline: CSR build (count / hierarchical scan / fill) -> GEMM1 ->
//           agg1(+b1,relu) -> GEMM2 (W_mu|W_lv fused) -> agg2 -> z.
// R2: replaced single-block k_scan (289us, 1 CU) with 3-kernel hierarchical
//     scan (partial sums -> scan block sums -> emit with wave shuffle-scan).

__global__ __launch_bounds__(256) void k_count(const int* __restrict__ coli,
                                               int* __restrict__ cnt, int E) {
    int e = blockIdx.x * 256 + threadIdx.x;
    if (e < E) atomicAdd(&cnt[coli[e]], 1);
}

// Per-block sums: 2048 elements / block (8 per thread).
__global__ __launch_bounds__(256) void k_partial(const int* __restrict__ cnt,
                                                 int* __restrict__ bsum, int N) {
    int t = threadIdx.x;
    int base = blockIdx.x * 2048 + t * 8;
    int s = 0;
#pragma unroll
    for (int i = 0; i < 8; i++) {
        int idx = base + i;
        if (idx < N) s += cnt[idx];
    }
#pragma unroll
    for (int d = 1; d < 64; d <<= 1) s += __shfl_xor(s, d, 64);
    __shared__ int wsum[4];
    int lane = t & 63, wid = t >> 6;
    if (lane == 0) wsum[wid] = s;
    __syncthreads();
    if (t == 0) bsum[blockIdx.x] = wsum[0] + wsum[1] + wsum[2] + wsum[3];
}

// Single wave: exclusive scan of block sums in-place; also rowptr[N]=E.
__global__ __launch_bounds__(64) void k_scanblk(int* __restrict__ bsum, int nblk,
                                                int* __restrict__ rowptr,
                                                int N, int E) {
    int lane = threadIdx.x;
    int carry = 0;
    for (int base = 0; base < nblk; base += 64) {
        int i = base + lane;
        int orig = (i < nblk) ? bsum[i] : 0;
        int v = orig;
#pragma unroll
        for (int d = 1; d < 64; d <<= 1) {
            int u = __shfl_up(v, d, 64);
            if (lane >= d) v += u;
        }
        int tot = __shfl(v, 63, 64);
        if (i < nblk) bsum[i] = carry + v - orig;  // exclusive
        carry += tot;
    }
    if (lane == 0) rowptr[N] = E;
}

// Recompute local exclusive prefix, add block offset, emit rowptr/cursor/dis.
__global__ __launch_bounds__(256) void k_emit(const int* __restrict__ cnt,
                                              const int* __restrict__ boff,
                                              int* __restrict__ rowptr,
                                              int* __restrict__ cursor,
                                              float* __restrict__ dis, int N) {
    int t = threadIdx.x;
    int base = blockIdx.x * 2048 + t * 8;
    int local[8];
    int s = 0;
#pragma unroll
    for (int i = 0; i < 8; i++) {
        int idx = base + i;
        local[i] = (idx < N) ? cnt[idx] : 0;
        s += local[i];
    }
    int lane = t & 63, wid = t >> 6;
    int v = s;
#pragma unroll
    for (int d = 1; d < 64; d <<= 1) {
        int u = __shfl_up(v, d, 64);
        if (lane >= d) v += u;
    }
    __shared__ int wsum[4];
    if (lane == 63) wsum[wid] = v;
    __syncthreads();
    int woff = 0;
    for (int w = 0; w < wid; w++) woff += wsum[w];
    int run = boff[blockIdx.x] + woff + (v - s);  // exclusive prefix of elem 0
#pragma unroll
    for (int i = 0; i < 8; i++) {
        int idx = base + i;
        if (idx < N) {
            rowptr[idx] = run;
            cursor[idx] = run;
            dis[idx] = rsqrtf((float)(local[i] + 1));  // +1 self loop
            run += local[i];
        }
    }
}

__global__ __launch_bounds__(256) void k_fill(const int* __restrict__ rowi,
                                              const int* __restrict__ coli,
                                              int* __restrict__ cursor,
                                              int* __restrict__ srcs, int E) {
    int e = blockIdx.x * 256 + threadIdx.x;
    if (e < E) {
        int c = coli[e];
        int pos = atomicAdd(&cursor[c], 1);
        srcs[pos] = rowi[e];
    }
}

__device__ inline float4 f4fma(float s, float4 w, float4 a) {
    a.x = fmaf(s, w.x, a.x);
    a.y = fmaf(s, w.y, a.y);
    a.z = fmaf(s, w.z, a.z);
    a.w = fmaf(s, w.w, a.w);
    return a;
}

// Y[M,128] = X[M,128] @ W[128,128]; W cols [0,split) from Wa (row stride
// split), cols [split,128) from Wb. Block: 64 rows x 128 cols; thread: 8x4.
__global__ __launch_bounds__(256) void k_gemm(const float* __restrict__ X,
                                              const float* __restrict__ Wa,
                                              const float* __restrict__ Wb,
                                              int split,
                                              float* __restrict__ Y, int M) {
    __shared__ float Ws[128][128];  // 64 KB
    int wbs = 128 - split;
    for (int i = threadIdx.x; i < 128 * 128; i += 256) {
        int k = i >> 7, j = i & 127;
        Ws[k][j] = (j < split) ? Wa[k * split + j] : Wb[k * wbs + (j - split)];
    }
    __syncthreads();

    int c4 = (threadIdx.x & 31) << 2;
    int r0 = blockIdx.x * 64 + (threadIdx.x >> 5) * 8;
    float4 acc[8];
#pragma unroll
    for (int r = 0; r < 8; r++) acc[r] = make_float4(0.f, 0.f, 0.f, 0.f);
    int rowidx[8];
#pragma unroll
    for (int r = 0; r < 8; r++) rowidx[r] = min(r0 + r, M - 1);

    for (int k = 0; k < 128; k += 4) {
        float4 w0 = *(const float4*)&Ws[k + 0][c4];
        float4 w1 = *(const float4*)&Ws[k + 1][c4];
        float4 w2 = *(const float4*)&Ws[k + 2][c4];
        float4 w3 = *(const float4*)&Ws[k + 3][c4];
#pragma unroll
        for (int r = 0; r < 8; r++) {
            float4 xv = *(const float4*)&X[rowidx[r] * 128 + k];
            acc[r] = f4fma(xv.x, w0, acc[r]);
            acc[r] = f4fma(xv.y, w1, acc[r]);
            acc[r] = f4fma(xv.z, w2, acc[r]);
            acc[r] = f4fma(xv.w, w3, acc[r]);
        }
    }
#pragma unroll
    for (int r = 0; r < 8; r++) {
        int row = r0 + r;
        if (row < M) *(float4*)&Y[row * 128 + c4] = acc[r];
    }
}

// out[i] = bias + dis_i * ( sum_{e:col=i} dis[src_e]*F[src_e] + dis_i*F[i] )
// One wave per node, 2 cols per lane.
__global__ __launch_bounds__(256) void k_agg(const float* __restrict__ F,
                                             const float* __restrict__ dis,
                                             const int* __restrict__ rowptr,
                                             const int* __restrict__ srcs,
                                             const float* __restrict__ ba,
                                             const float* __restrict__ bb,
                                             int split,
                                             float* __restrict__ outA,
                                             float* __restrict__ outB,
                                             int relu, int N) {
    int node = blockIdx.x * 4 + (threadIdx.x >> 6);
    if (node >= N) return;
    int lane = threadIdx.x & 63;
    int j = lane << 1;
    const float2* Fr = (const float2*)F;
    float di = dis[node];
    float2 sv = Fr[node * 64 + lane];
    float ax = di * sv.x;
    float ay = di * sv.y;
    int s = rowptr[node], e = rowptr[node + 1];
    for (int t = s; t < e; t++) {
        int sr = srcs[t];
        float w = dis[sr];
        float2 f = Fr[sr * 64 + lane];
        ax = fmaf(w, f.x, ax);
        ay = fmaf(w, f.y, ay);
    }
    ax *= di;
    ay *= di;
    float* op;
    int jj;
    float b0, b1v;
    if (j < split) { op = outA; jj = j; b0 = ba[jj]; b1v = ba[jj + 1]; }
    else           { op = outB; jj = j - split; b0 = bb[jj]; b1v = bb[jj + 1]; }
    float o0 = ax + b0, o1 = ay + b1v;
    if (relu) { o0 = fmaxf(o0, 0.f); o1 = fmaxf(o1, 0.f); }
    *(float2*)&op[node * split + jj] = make_float2(o0, o1);
}

__global__ __launch_bounds__(256) void k_final(const float* __restrict__ mu,
                                               const float* __restrict__ lv,
                                               const float* __restrict__ eps,
                                               float* __restrict__ z, int n) {
    int i = blockIdx.x * 256 + threadIdx.x;
    if (i < n) z[i] = fmaf(eps[i], expf(0.5f * lv[i]), mu[i]);
}

extern "C" void kernel_launch(void* const* d_in, const int* in_sizes, int n_in,
                              void* d_out, int out_size, void* d_ws, size_t ws_size,
                              hipStream_t stream) {
    const float* x   = (const float*)d_in[0];
    const int*   ei  = (const int*)d_in[1];
    const float* W1  = (const float*)d_in[2];
    const float* b1  = (const float*)d_in[3];
    const float* Wmu = (const float*)d_in[4];
    const float* bmu = (const float*)d_in[5];
    const float* Wlv = (const float*)d_in[6];
    const float* blv = (const float*)d_in[7];
    const float* eps = (const float*)d_in[8];

    int N = in_sizes[0] / 128;   // 100000
    int E = in_sizes[1] / 2;     // 1600000
    const int* rowi = ei;        // edge_index[0]
    const int* coli = ei + E;    // edge_index[1]

    char* ws = (char*)d_ws;
    size_t off = 0;
    auto alloc = [&](size_t bytes) -> void* {
        void* p = ws + off;
        off += (bytes + 255) & ~(size_t)255;
        return p;
    };
    float* bufA   = (float*)alloc((size_t)N * 128 * 4);  // h_pre, then hcat
    float* bufB   = (float*)alloc((size_t)N * 128 * 4);  // h
    float* dis    = (float*)alloc((size_t)N * 4);
    int*   cnt    = (int*)alloc((size_t)N * 4);
    int*   rowptr = (int*)alloc((size_t)(N + 1) * 4);
    int*   cursor = (int*)alloc((size_t)N * 4);
    int*   srcs   = (int*)alloc((size_t)E * 4);
    int nblk = (N + 2047) / 2048;
    int*   bsum   = (int*)alloc((size_t)nblk * 4);

    float* zo  = (float*)d_out;                 // [N,64]
    float* muo = zo + (size_t)N * 64;           // [N,64]
    float* lvo = zo + (size_t)N * 128;          // [N,64]

    hipMemsetAsync(cnt, 0, (size_t)N * 4, stream);
    k_count<<<(E + 255) / 256, 256, 0, stream>>>(coli, cnt, E);
    k_partial<<<nblk, 256, 0, stream>>>(cnt, bsum, N);
    k_scanblk<<<1, 64, 0, stream>>>(bsum, nblk, rowptr, N, E);
    k_emit<<<nblk, 256, 0, stream>>>(cnt, bsum, rowptr, cursor, dis, N);
    k_fill<<<(E + 255) / 256, 256, 0, stream>>>(rowi, coli, cursor, srcs, E);

    k_gemm<<<(N + 63) / 64, 256, 0, stream>>>(x, W1, W1, 128, bufA, N);
    k_agg<<<(N + 3) / 4, 256, 0, stream>>>(bufA, dis, rowptr, srcs,
                                           b1, b1, 128, bufB, bufB, 1, N);
    k_gemm<<<(N + 63) / 64, 256, 0, stream>>>(bufB, Wmu, Wlv, 64, bufA, N);
    k_agg<<<(N + 3) / 4, 256, 0, stream>>>(bufA, dis, rowptr, srcs,
                                           bmu, blv, 64, muo, lvo, 0, N);
    k_final<<<((N * 64) + 255) / 256, 256, 0, stream>>>(muo, lvo, eps, zo, N * 64);
}

// Round 3
// 642.673 us; speedup vs baseline: 1.7200x; 1.3019x over previous
//
#include <hip/hip_runtime.h>
#include <math.h>

// VGAE forward: 3x GCNConv + reparameterize.
// Pipeline: CSR build (count / hierarchical scan / fill) -> GEMM1(dis-scaled,
//           bf16 out) -> agg1(+b1,relu,bf16 out) -> GEMM2 (W_mu|W_lv fused,
//           dis-scaled, bf16 out) -> agg2 (f32 into d_out mu/lv) -> z.
// R2: hierarchical scan (was 289us single-block -> ~10us).
// R3: bf16 intermediate features (gather rows 512B->256B, 25.6MB L3-resident),
//     dis pre-scaled into GEMM epilogue (edge loop = index load + row load),
//     edge loop unrolled x4 (4 gathers in flight per chain step).

__device__ inline float bf2f(unsigned short u) {
    union { unsigned int i; float f; } c;
    c.i = ((unsigned int)u) << 16;
    return c.f;
}
__device__ inline unsigned short f2bf(float f) {
    union { float f; unsigned int i; } c;
    c.f = f;
    unsigned int r = c.i + 0x7FFF + ((c.i >> 16) & 1);  // round-nearest-even
    return (unsigned short)(r >> 16);
}

__global__ __launch_bounds__(256) void k_count(const int* __restrict__ coli,
                                               int* __restrict__ cnt, int E) {
    int e = blockIdx.x * 256 + threadIdx.x;
    if (e < E) atomicAdd(&cnt[coli[e]], 1);
}

// Per-block sums: 2048 elements / block (8 per thread).
__global__ __launch_bounds__(256) void k_partial(const int* __restrict__ cnt,
                                                 int* __restrict__ bsum, int N) {
    int t = threadIdx.x;
    int base = blockIdx.x * 2048 + t * 8;
    int s = 0;
#pragma unroll
    for (int i = 0; i < 8; i++) {
        int idx = base + i;
        if (idx < N) s += cnt[idx];
    }
#pragma unroll
    for (int d = 1; d < 64; d <<= 1) s += __shfl_xor(s, d, 64);
    __shared__ int wsum[4];
    int lane = t & 63, wid = t >> 6;
    if (lane == 0) wsum[wid] = s;
    __syncthreads();
    if (t == 0) bsum[blockIdx.x] = wsum[0] + wsum[1] + wsum[2] + wsum[3];
}

// Single wave: exclusive scan of block sums in-place; also rowptr[N]=E.
__global__ __launch_bounds__(64) void k_scanblk(int* __restrict__ bsum, int nblk,
                                                int* __restrict__ rowptr,
                                                int N, int E) {
    int lane = threadIdx.x;
    int carry = 0;
    for (int base = 0; base < nblk; base += 64) {
        int i = base + lane;
        int orig = (i < nblk) ? bsum[i] : 0;
        int v = orig;
#pragma unroll
        for (int d = 1; d < 64; d <<= 1) {
            int u = __shfl_up(v, d, 64);
            if (lane >= d) v += u;
        }
        int tot = __shfl(v, 63, 64);
        if (i < nblk) bsum[i] = carry + v - orig;  // exclusive
        carry += tot;
    }
    if (lane == 0) rowptr[N] = E;
}

// Recompute local exclusive prefix, add block offset, emit rowptr/cursor/dis.
__global__ __launch_bounds__(256) void k_emit(const int* __restrict__ cnt,
                                              const int* __restrict__ boff,
                                              int* __restrict__ rowptr,
                                              int* __restrict__ cursor,
                                              float* __restrict__ dis, int N) {
    int t = threadIdx.x;
    int base = blockIdx.x * 2048 + t * 8;
    int local[8];
    int s = 0;
#pragma unroll
    for (int i = 0; i < 8; i++) {
        int idx = base + i;
        local[i] = (idx < N) ? cnt[idx] : 0;
        s += local[i];
    }
    int lane = t & 63, wid = t >> 6;
    int v = s;
#pragma unroll
    for (int d = 1; d < 64; d <<= 1) {
        int u = __shfl_up(v, d, 64);
        if (lane >= d) v += u;
    }
    __shared__ int wsum[4];
    if (lane == 63) wsum[wid] = v;
    __syncthreads();
    int woff = 0;
    for (int w = 0; w < wid; w++) woff += wsum[w];
    int run = boff[blockIdx.x] + woff + (v - s);  // exclusive prefix of elem 0
#pragma unroll
    for (int i = 0; i < 8; i++) {
        int idx = base + i;
        if (idx < N) {
            rowptr[idx] = run;
            cursor[idx] = run;
            dis[idx] = rsqrtf((float)(local[i] + 1));  // +1 self loop
            run += local[i];
        }
    }
}

__global__ __launch_bounds__(256) void k_fill(const int* __restrict__ rowi,
                                              const int* __restrict__ coli,
                                              int* __restrict__ cursor,
                                              int* __restrict__ srcs, int E) {
    int e = blockIdx.x * 256 + threadIdx.x;
    if (e < E) {
        int c = coli[e];
        int pos = atomicAdd(&cursor[c], 1);
        srcs[pos] = rowi[e];
    }
}

__device__ inline float4 f4fma(float s, float4 w, float4 a) {
    a.x = fmaf(s, w.x, a.x);
    a.y = fmaf(s, w.y, a.y);
    a.z = fmaf(s, w.z, a.z);
    a.w = fmaf(s, w.w, a.w);
    return a;
}

// Y[M,128] = dis[row] * (X[M,128] @ W[128,128]) -> bf16.
// W cols [0,split) from Wa (row stride split), cols [split,128) from Wb.
// Block: 64 rows x 128 cols; thread: 8 rows x 4 cols. XBF: X is bf16.
template <bool XBF>
__global__ __launch_bounds__(256) void k_gemm(const void* __restrict__ Xv,
                                              const float* __restrict__ Wa,
                                              const float* __restrict__ Wb,
                                              int split,
                                              const float* __restrict__ dis,
                                              unsigned short* __restrict__ Y,
                                              int M) {
    __shared__ float Ws[128][128];  // 64 KB
    int wbs = 128 - split;
    for (int i = threadIdx.x; i < 128 * 128; i += 256) {
        int k = i >> 7, j = i & 127;
        Ws[k][j] = (j < split) ? Wa[k * split + j] : Wb[k * wbs + (j - split)];
    }
    __syncthreads();

    int c4 = (threadIdx.x & 31) << 2;
    int r0 = blockIdx.x * 64 + (threadIdx.x >> 5) * 8;
    float4 acc[8];
#pragma unroll
    for (int r = 0; r < 8; r++) acc[r] = make_float4(0.f, 0.f, 0.f, 0.f);
    int rowidx[8];
#pragma unroll
    for (int r = 0; r < 8; r++) rowidx[r] = min(r0 + r, M - 1);

    for (int k = 0; k < 128; k += 4) {
        float4 w0 = *(const float4*)&Ws[k + 0][c4];
        float4 w1 = *(const float4*)&Ws[k + 1][c4];
        float4 w2 = *(const float4*)&Ws[k + 2][c4];
        float4 w3 = *(const float4*)&Ws[k + 3][c4];
#pragma unroll
        for (int r = 0; r < 8; r++) {
            float4 xv;
            if (XBF) {
                ushort4 u = ((const ushort4*)Xv)[rowidx[r] * 32 + (k >> 2)];
                xv = make_float4(bf2f(u.x), bf2f(u.y), bf2f(u.z), bf2f(u.w));
            } else {
                xv = ((const float4*)Xv)[rowidx[r] * 32 + (k >> 2)];
            }
            acc[r] = f4fma(xv.x, w0, acc[r]);
            acc[r] = f4fma(xv.y, w1, acc[r]);
            acc[r] = f4fma(xv.z, w2, acc[r]);
            acc[r] = f4fma(xv.w, w3, acc[r]);
        }
    }
#pragma unroll
    for (int r = 0; r < 8; r++) {
        int row = r0 + r;
        if (row < M) {
            float d = dis[row];
            ushort4 o;
            o.x = f2bf(d * acc[r].x);
            o.y = f2bf(d * acc[r].y);
            o.z = f2bf(d * acc[r].z);
            o.w = f2bf(d * acc[r].w);
            *(ushort4*)&Y[row * 128 + c4] = o;
        }
    }
}

// F is dis-prescaled bf16 [N,128]. out[i] = bias + dis_i * (F[i] + sum F[src]).
// One wave per node, 2 cols per lane, edge loop unrolled x4.
// OBF: output bf16 (row stride 128, relu); else f32 split into outA/outB (64).
template <bool OBF>
__global__ __launch_bounds__(256) void k_agg(const ushort2* __restrict__ F,
                                             const float* __restrict__ dis,
                                             const int* __restrict__ rowptr,
                                             const int* __restrict__ srcs,
                                             const float* __restrict__ ba,
                                             const float* __restrict__ bb,
                                             void* __restrict__ outA,
                                             void* __restrict__ outB,
                                             int N) {
    int node = blockIdx.x * 4 + (threadIdx.x >> 6);
    if (node >= N) return;
    int lane = threadIdx.x & 63;
    ushort2 sv = F[node * 64 + lane];
    float ax = bf2f(sv.x);  // self term: F'[i] = dis_i * feat_i
    float ay = bf2f(sv.y);
    int s = rowptr[node], e = rowptr[node + 1];
    int t = s;
    for (; t + 4 <= e; t += 4) {
        int i0 = srcs[t + 0], i1 = srcs[t + 1];
        int i2 = srcs[t + 2], i3 = srcs[t + 3];
        ushort2 f0 = F[i0 * 64 + lane];
        ushort2 f1 = F[i1 * 64 + lane];
        ushort2 f2 = F[i2 * 64 + lane];
        ushort2 f3 = F[i3 * 64 + lane];
        ax += bf2f(f0.x) + bf2f(f1.x) + bf2f(f2.x) + bf2f(f3.x);
        ay += bf2f(f0.y) + bf2f(f1.y) + bf2f(f2.y) + bf2f(f3.y);
    }
    for (; t < e; t++) {
        int sr = srcs[t];
        ushort2 f = F[sr * 64 + lane];
        ax += bf2f(f.x);
        ay += bf2f(f.y);
    }
    float di = dis[node];
    int j = lane << 1;
    if (OBF) {
        float o0 = fmaxf(fmaf(di, ax, ba[j]), 0.f);
        float o1 = fmaxf(fmaf(di, ay, ba[j + 1]), 0.f);
        ushort2 o;
        o.x = f2bf(o0);
        o.y = f2bf(o1);
        ((ushort2*)outA)[node * 64 + lane] = o;
    } else {
        float* op;
        int jj;
        const float* bp;
        if (j < 64) { op = (float*)outA; jj = j; bp = ba; }
        else        { op = (float*)outB; jj = j - 64; bp = bb; }
        float o0 = fmaf(di, ax, bp[jj]);
        float o1 = fmaf(di, ay, bp[jj + 1]);
        *(float2*)&op[node * 64 + jj] = make_float2(o0, o1);
    }
}

__global__ __launch_bounds__(256) void k_final(const float* __restrict__ mu,
                                               const float* __restrict__ lv,
                                               const float* __restrict__ eps,
                                               float* __restrict__ z, int n) {
    int i = blockIdx.x * 256 + threadIdx.x;
    if (i < n) z[i] = fmaf(eps[i], expf(0.5f * lv[i]), mu[i]);
}

extern "C" void kernel_launch(void* const* d_in, const int* in_sizes, int n_in,
                              void* d_out, int out_size, void* d_ws, size_t ws_size,
                              hipStream_t stream) {
    const float* x   = (const float*)d_in[0];
    const int*   ei  = (const int*)d_in[1];
    const float* W1  = (const float*)d_in[2];
    const float* b1  = (const float*)d_in[3];
    const float* Wmu = (const float*)d_in[4];
    const float* bmu = (const float*)d_in[5];
    const float* Wlv = (const float*)d_in[6];
    const float* blv = (const float*)d_in[7];
    const float* eps = (const float*)d_in[8];

    int N = in_sizes[0] / 128;   // 100000
    int E = in_sizes[1] / 2;     // 1600000
    const int* rowi = ei;        // edge_index[0]
    const int* coli = ei + E;    // edge_index[1]

    char* ws = (char*)d_ws;
    size_t off = 0;
    auto alloc = [&](size_t bytes) -> void* {
        void* p = ws + off;
        off += (bytes + 255) & ~(size_t)255;
        return p;
    };
    unsigned short* bufA = (unsigned short*)alloc((size_t)N * 128 * 2);  // F'1, F'2
    unsigned short* bufB = (unsigned short*)alloc((size_t)N * 128 * 2);  // h (bf16)
    float* dis    = (float*)alloc((size_t)N * 4);
    int*   cnt    = (int*)alloc((size_t)N * 4);
    int*   rowptr = (int*)alloc((size_t)(N + 1) * 4);
    int*   cursor = (int*)alloc((size_t)N * 4);
    int*   srcs   = (int*)alloc((size_t)E * 4);
    int nblk = (N + 2047) / 2048;
    int*   bsum   = (int*)alloc((size_t)nblk * 4);

    float* zo  = (float*)d_out;                 // [N,64]
    float* muo = zo + (size_t)N * 64;           // [N,64]
    float* lvo = zo + (size_t)N * 128;          // [N,64]

    hipMemsetAsync(cnt, 0, (size_t)N * 4, stream);
    k_count<<<(E + 255) / 256, 256, 0, stream>>>(coli, cnt, E);
    k_partial<<<nblk, 256, 0, stream>>>(cnt, bsum, N);
    k_scanblk<<<1, 64, 0, stream>>>(bsum, nblk, rowptr, N, E);
    k_emit<<<nblk, 256, 0, stream>>>(cnt, bsum, rowptr, cursor, dis, N);
    k_fill<<<(E + 255) / 256, 256, 0, stream>>>(rowi, coli, cursor, srcs, E);

    // F'1 = dis . (x @ W1)   (bf16)
    k_gemm<false><<<(N + 63) / 64, 256, 0, stream>>>(x, W1, W1, 128, dis, bufA, N);
    // h = relu(dis . (F'1[i] + sum F'1[src]) + b1)   (bf16)
    k_agg<true><<<(N + 3) / 4, 256, 0, stream>>>((const ushort2*)bufA, dis, rowptr,
                                                 srcs, b1, b1, bufB, bufB, N);
    // F'2 = dis . (h @ [Wmu|Wlv])   (bf16)
    k_gemm<true><<<(N + 63) / 64, 256, 0, stream>>>(bufB, Wmu, Wlv, 64, dis, bufA, N);
    // mu/lv = dis . (F'2[i] + sum F'2[src]) + b   (f32, direct to d_out)
    k_agg<false><<<(N + 3) / 4, 256, 0, stream>>>((const ushort2*)bufA, dis, rowptr,
                                                  srcs, bmu, blv, muo, lvo, N);
    k_final<<<((N * 64) + 255) / 256, 256, 0, stream>>>(muo, lvo, eps, zo, N * 64);
}

// Round 4
// 524.133 us; speedup vs baseline: 2.1090x; 1.2262x over previous
//
#include <hip/hip_runtime.h>
#include <math.h>

// VGAE forward: 3x GCNConv + reparameterize.
// Pipeline: bucket-sort CSR build (bhist/bscan/bucket/fill2) -> GEMM1
//           (dis-scaled, bf16 out) -> agg1(+b1,relu,bf16) -> GEMM2
//           (W_mu|W_lv fused, dis-scaled, bf16) -> agg2 (f32 to d_out) -> z.
// R2: hierarchical scan (289us single-block scan -> ~10us).
// R3: bf16 intermediates, dis pre-scaled in GEMM epilogue, agg unroll x4.
// R4: scatter-free CSR build. Old k_fill wrote 105MB (64B-line amplification
//     of 1.6M random 4B stores, 125us). Now: two-level bucket sort, all
//     random scatters in LDS, global writes are coalesced bursts.

#define SHIFT 9            // nodes per bucket = 512
#define EPB 4096           // edges per k_bucket block
#define HEPB 8192          // edges per k_bhist block
#define CAP 15104          // fill2 LDS srcs capacity (avg bucket = 8192)

__device__ inline float bf2f(unsigned short u) {
    union { unsigned int i; float f; } c;
    c.i = ((unsigned int)u) << 16;
    return c.f;
}
__device__ inline unsigned short f2bf(float f) {
    union { float f; unsigned int i; } c;
    c.f = f;
    unsigned int r = c.i + 0x7FFF + ((c.i >> 16) & 1);  // round-nearest-even
    return (unsigned short)(r >> 16);
}

// Block-wide (256 thr) exclusive scan of one int per thread.
__device__ inline int scan256(int v, int* wsum) {
    __syncthreads();  // protect wsum reuse across calls
    int lane = threadIdx.x & 63, wid = threadIdx.x >> 6;
    int s = v;
#pragma unroll
    for (int d = 1; d < 64; d <<= 1) {
        int u = __shfl_up(s, d, 64);
        if (lane >= d) s += u;
    }
    if (lane == 63) wsum[wid] = s;
    __syncthreads();
    int off = 0;
    for (int w = 0; w < wid; w++) off += wsum[w];
    return off + s - v;
}

// Per-block LDS histogram of bucket ids -> global bucket histogram.
__global__ __launch_bounds__(256) void k_bhist(const int* __restrict__ coli,
                                               int* __restrict__ gbh,
                                               int E, int NB) {
    __shared__ int lh[256];
    int t = threadIdx.x;
    lh[t] = 0;
    __syncthreads();
    int base = blockIdx.x * HEPB;
    for (int i = t; i < HEPB; i += 256) {
        int e = base + i;
        if (e < E) atomicAdd(&lh[coli[e] >> SHIFT], 1);
    }
    __syncthreads();
    if (t < NB && lh[t]) atomicAdd(&gbh[t], lh[t]);
}

// One block: scan bucket sums -> bucketptr + cursors; rowptr[N]=E.
__global__ __launch_bounds__(256) void k_bscan(const int* __restrict__ gbh,
                                               int* __restrict__ bptr,
                                               int* __restrict__ bcur,
                                               int NB, int E,
                                               int* __restrict__ rowptr, int N) {
    __shared__ int wsum[4];
    int t = threadIdx.x;
    int v = (t < NB) ? gbh[t] : 0;
    int e = scan256(v, wsum);
    if (t < NB) { bptr[t] = e; bcur[t] = e; }
    if (t == 0) { bptr[NB] = E; rowptr[N] = E; }
}

// Bin EPB edges into LDS by bucket, burst-write (row,col) records to
// contiguous per-bucket runs (one global atomic per bucket per block).
__global__ __launch_bounds__(256) void k_bucket(const int* __restrict__ rowi,
                                                const int* __restrict__ coli,
                                                int* __restrict__ bcur,
                                                int2* __restrict__ recs,
                                                int E, int NB) {
    __shared__ int lh[256], excl[256], lcur[256], gbase[256], wsum[4];
    __shared__ int2 stage[EPB];
    int t = threadIdx.x;
    lh[t] = 0;
    __syncthreads();
    int base = blockIdx.x * EPB;
    int nE = min(EPB, E - base);
    int2 my[16];
    int cnt = 0;
#pragma unroll
    for (int i = 0; i < 16; i++) {
        int idx = t + i * 256;
        if (idx < nE) {
            my[cnt].x = rowi[base + idx];
            my[cnt].y = coli[base + idx];
            atomicAdd(&lh[my[cnt].y >> SHIFT], 1);
            cnt++;
        }
    }
    __syncthreads();
    int myh = lh[t];
    int ex = scan256(myh, wsum);
    excl[t] = ex;
    lcur[t] = ex;
    if (t < NB && myh) gbase[t] = atomicAdd(&bcur[t], myh);
    __syncthreads();
    for (int i = 0; i < cnt; i++) {
        int p = atomicAdd(&lcur[my[i].y >> SHIFT], 1);
        stage[p] = my[i];
    }
    __syncthreads();
    for (int i = t; i < nE; i += 256) {
        int2 r = stage[i];
        int bb = r.y >> SHIFT;
        recs[gbase[bb] + (i - excl[bb])] = r;
    }
}

// One block per bucket: local histogram -> rowptr/dis, LDS scatter of rows,
// coalesced burst write of srcs.
__global__ __launch_bounds__(256) void k_fill2(const int2* __restrict__ recs,
                                               const int* __restrict__ bptr,
                                               int* __restrict__ rowptr,
                                               float* __restrict__ dis,
                                               int* __restrict__ srcs, int N) {
    __shared__ int hist[512], excl[512], wsum[4];
    __shared__ int srcsL[CAP];
    int t = threadIdx.x;
    int b = blockIdx.x;
    int nbase = b << SHIFT;
    int start = bptr[b], end = bptr[b + 1];
    int cnt = end - start;
    hist[t] = 0;
    hist[t + 256] = 0;
    __syncthreads();
    for (int i = start + t; i < end; i += 256)
        atomicAdd(&hist[recs[i].y - nbase], 1);
    __syncthreads();
    int h0 = hist[2 * t], h1 = hist[2 * t + 1];
    int e0 = scan256(h0 + h1, wsum);
    excl[2 * t] = e0;
    excl[2 * t + 1] = e0 + h0;
    int n0 = nbase + 2 * t, n1 = nbase + 2 * t + 1;
    if (n0 < N) { rowptr[n0] = start + e0;      dis[n0] = rsqrtf((float)(h0 + 1)); }
    if (n1 < N) { rowptr[n1] = start + e0 + h0; dis[n1] = rsqrtf((float)(h1 + 1)); }
    __syncthreads();
    if (cnt <= CAP) {
        for (int i = start + t; i < end; i += 256) {
            int2 r = recs[i];
            int p = atomicAdd(&excl[r.y - nbase], 1);
            srcsL[p] = r.x;
        }
        __syncthreads();
        for (int i = t; i < cnt; i += 256) srcs[start + i] = srcsL[i];
    } else {  // pathological bucket: direct scatter (correct, slow, never hit
              // for ~uniform data)
        for (int i = start + t; i < end; i += 256) {
            int2 r = recs[i];
            int p = atomicAdd(&excl[r.y - nbase], 1);
            srcs[start + p] = r.x;
        }
    }
}

__device__ inline float4 f4fma(float s, float4 w, float4 a) {
    a.x = fmaf(s, w.x, a.x);
    a.y = fmaf(s, w.y, a.y);
    a.z = fmaf(s, w.z, a.z);
    a.w = fmaf(s, w.w, a.w);
    return a;
}

// Y[M,128] = dis[row] * (X[M,128] @ W[128,128]) -> bf16.
// W cols [0,split) from Wa (row stride split), cols [split,128) from Wb.
// Block: 64 rows x 128 cols; thread: 8 rows x 4 cols. XBF: X is bf16.
template <bool XBF>
__global__ __launch_bounds__(256) void k_gemm(const void* __restrict__ Xv,
                                              const float* __restrict__ Wa,
                                              const float* __restrict__ Wb,
                                              int split,
                                              const float* __restrict__ dis,
                                              unsigned short* __restrict__ Y,
                                              int M) {
    __shared__ float Ws[128][128];  // 64 KB
    int wbs = 128 - split;
    for (int i = threadIdx.x; i < 128 * 128; i += 256) {
        int k = i >> 7, j = i & 127;
        Ws[k][j] = (j < split) ? Wa[k * split + j] : Wb[k * wbs + (j - split)];
    }
    __syncthreads();

    int c4 = (threadIdx.x & 31) << 2;
    int r0 = blockIdx.x * 64 + (threadIdx.x >> 5) * 8;
    float4 acc[8];
#pragma unroll
    for (int r = 0; r < 8; r++) acc[r] = make_float4(0.f, 0.f, 0.f, 0.f);
    int rowidx[8];
#pragma unroll
    for (int r = 0; r < 8; r++) rowidx[r] = min(r0 + r, M - 1);

    for (int k = 0; k < 128; k += 4) {
        float4 w0 = *(const float4*)&Ws[k + 0][c4];
        float4 w1 = *(const float4*)&Ws[k + 1][c4];
        float4 w2 = *(const float4*)&Ws[k + 2][c4];
        float4 w3 = *(const float4*)&Ws[k + 3][c4];
#pragma unroll
        for (int r = 0; r < 8; r++) {
            float4 xv;
            if (XBF) {
                ushort4 u = ((const ushort4*)Xv)[rowidx[r] * 32 + (k >> 2)];
                xv = make_float4(bf2f(u.x), bf2f(u.y), bf2f(u.z), bf2f(u.w));
            } else {
                xv = ((const float4*)Xv)[rowidx[r] * 32 + (k >> 2)];
            }
            acc[r] = f4fma(xv.x, w0, acc[r]);
            acc[r] = f4fma(xv.y, w1, acc[r]);
            acc[r] = f4fma(xv.z, w2, acc[r]);
            acc[r] = f4fma(xv.w, w3, acc[r]);
        }
    }
#pragma unroll
    for (int r = 0; r < 8; r++) {
        int row = r0 + r;
        if (row < M) {
            float d = dis[row];
            ushort4 o;
            o.x = f2bf(d * acc[r].x);
            o.y = f2bf(d * acc[r].y);
            o.z = f2bf(d * acc[r].z);
            o.w = f2bf(d * acc[r].w);
            *(ushort4*)&Y[row * 128 + c4] = o;
        }
    }
}

// F is dis-prescaled bf16 [N,128]. out[i] = bias + dis_i * (F[i] + sum F[src]).
// One wave per node, 2 cols per lane, edge loop unrolled x4.
// OBF: output bf16 (row stride 128, relu); else f32 split into outA/outB (64).
template <bool OBF>
__global__ __launch_bounds__(256) void k_agg(const ushort2* __restrict__ F,
                                             const float* __restrict__ dis,
                                             const int* __restrict__ rowptr,
                                             const int* __restrict__ srcs,
                                             const float* __restrict__ ba,
                                             const float* __restrict__ bb,
                                             void* __restrict__ outA,
                                             void* __restrict__ outB,
                                             int N) {
    int node = blockIdx.x * 4 + (threadIdx.x >> 6);
    if (node >= N) return;
    int lane = threadIdx.x & 63;
    ushort2 sv = F[node * 64 + lane];
    float ax = bf2f(sv.x);  // self term: F'[i] = dis_i * feat_i
    float ay = bf2f(sv.y);
    int s = rowptr[node], e = rowptr[node + 1];
    int t = s;
    for (; t + 4 <= e; t += 4) {
        int i0 = srcs[t + 0], i1 = srcs[t + 1];
        int i2 = srcs[t + 2], i3 = srcs[t + 3];
        ushort2 f0 = F[i0 * 64 + lane];
        ushort2 f1 = F[i1 * 64 + lane];
        ushort2 f2 = F[i2 * 64 + lane];
        ushort2 f3 = F[i3 * 64 + lane];
        ax += bf2f(f0.x) + bf2f(f1.x) + bf2f(f2.x) + bf2f(f3.x);
        ay += bf2f(f0.y) + bf2f(f1.y) + bf2f(f2.y) + bf2f(f3.y);
    }
    for (; t < e; t++) {
        int sr = srcs[t];
        ushort2 f = F[sr * 64 + lane];
        ax += bf2f(f.x);
        ay += bf2f(f.y);
    }
    float di = dis[node];
    int j = lane << 1;
    if (OBF) {
        float o0 = fmaxf(fmaf(di, ax, ba[j]), 0.f);
        float o1 = fmaxf(fmaf(di, ay, ba[j + 1]), 0.f);
        ushort2 o;
        o.x = f2bf(o0);
        o.y = f2bf(o1);
        ((ushort2*)outA)[node * 64 + lane] = o;
    } else {
        float* op;
        int jj;
        const float* bp;
        if (j < 64) { op = (float*)outA; jj = j; bp = ba; }
        else        { op = (float*)outB; jj = j - 64; bp = bb; }
        float o0 = fmaf(di, ax, bp[jj]);
        float o1 = fmaf(di, ay, bp[jj + 1]);
        *(float2*)&op[node * 64 + jj] = make_float2(o0, o1);
    }
}

__global__ __launch_bounds__(256) void k_final(const float* __restrict__ mu,
                                               const float* __restrict__ lv,
                                               const float* __restrict__ eps,
                                               float* __restrict__ z, int n) {
    int i = blockIdx.x * 256 + threadIdx.x;
    if (i < n) z[i] = fmaf(eps[i], expf(0.5f * lv[i]), mu[i]);
}

extern "C" void kernel_launch(void* const* d_in, const int* in_sizes, int n_in,
                              void* d_out, int out_size, void* d_ws, size_t ws_size,
                              hipStream_t stream) {
    const float* x   = (const float*)d_in[0];
    const int*   ei  = (const int*)d_in[1];
    const float* W1  = (const float*)d_in[2];
    const float* b1  = (const float*)d_in[3];
    const float* Wmu = (const float*)d_in[4];
    const float* bmu = (const float*)d_in[5];
    const float* Wlv = (const float*)d_in[6];
    const float* blv = (const float*)d_in[7];
    const float* eps = (const float*)d_in[8];

    int N = in_sizes[0] / 128;   // 100000
    int E = in_sizes[1] / 2;     // 1600000
    const int* rowi = ei;        // edge_index[0]
    const int* coli = ei + E;    // edge_index[1]
    int NB = (N + (1 << SHIFT) - 1) >> SHIFT;   // 196 buckets

    char* ws = (char*)d_ws;
    size_t off = 0;
    auto alloc = [&](size_t bytes) -> void* {
        void* p = ws + off;
        off += (bytes + 255) & ~(size_t)255;
        return p;
    };
    unsigned short* bufA = (unsigned short*)alloc((size_t)N * 128 * 2);  // F'1, F'2
    unsigned short* bufB = (unsigned short*)alloc((size_t)N * 128 * 2);  // h (bf16)
    float* dis    = (float*)alloc((size_t)N * 4);
    int*   rowptr = (int*)alloc((size_t)(N + 1) * 4);
    int*   srcs   = (int*)alloc((size_t)E * 4);
    int2*  recs   = (int2*)alloc((size_t)E * 8);
    int*   bhist  = (int*)alloc((size_t)NB * 4);
    int*   bptr   = (int*)alloc((size_t)(NB + 1) * 4);
    int*   bcur   = (int*)alloc((size_t)NB * 4);

    float* zo  = (float*)d_out;                 // [N,64]
    float* muo = zo + (size_t)N * 64;           // [N,64]
    float* lvo = zo + (size_t)N * 128;          // [N,64]

    hipMemsetAsync(bhist, 0, (size_t)NB * 4, stream);
    k_bhist<<<(E + HEPB - 1) / HEPB, 256, 0, stream>>>(coli, bhist, E, NB);
    k_bscan<<<1, 256, 0, stream>>>(bhist, bptr, bcur, NB, E, rowptr, N);
    k_bucket<<<(E + EPB - 1) / EPB, 256, 0, stream>>>(rowi, coli, bcur, recs, E, NB);
    k_fill2<<<NB, 256, 0, stream>>>(recs, bptr, rowptr, dis, srcs, N);

    // F'1 = dis . (x @ W1)   (bf16)
    k_gemm<false><<<(N + 63) / 64, 256, 0, stream>>>(x, W1, W1, 128, dis, bufA, N);
    // h = relu(dis . (F'1[i] + sum F'1[src]) + b1)   (bf16)
    k_agg<true><<<(N + 3) / 4, 256, 0, stream>>>((const ushort2*)bufA, dis, rowptr,
                                                 srcs, b1, b1, bufB, bufB, N);
    // F'2 = dis . (h @ [Wmu|Wlv])   (bf16)
    k_gemm<true><<<(N + 63) / 64, 256, 0, stream>>>(bufB, Wmu, Wlv, 64, dis, bufA, N);
    // mu/lv = dis . (F'2[i] + sum F'2[src]) + b   (f32, direct to d_out)
    k_agg<false><<<(N + 3) / 4, 256, 0, stream>>>((const ushort2*)bufA, dis, rowptr,
                                                  srcs, bmu, blv, muo, lvo, N);
    k_final<<<((N * 64) + 255) / 256, 256, 0, stream>>>(muo, lvo, eps, zo, N * 64);
}

// Round 5
// 432.777 us; speedup vs baseline: 2.5541x; 1.2111x over previous
//
#include <hip/hip_runtime.h>
#include <math.h>

// VGAE forward: 3x GCNConv + reparameterize.
// Pipeline: bucket-sort CSR build (bhist/bscan/bucket/fill2) -> MFMA GEMM1
//           (dis-scaled, f16 out) -> agg1(+b1,relu,f16) -> MFMA GEMM2
//           (W_mu|W_lv fused, dis-scaled, f16) -> agg2 (f32 to d_out) -> z.
// R2: hierarchical scan (289us single-block scan -> ~10us).
// R3: 16-bit intermediates, dis pre-scaled in GEMM epilogue, agg unroll x4.
// R4: scatter-free bucket-sort CSR build (k_fill 125us scatter -> ~25us).
// R5: f32 VALU GEMM (98us, MfmaUtil=0) -> mfma_f32_16x16x32_f16. W staged
//     swizzled in 32KB LDS then hoisted to 128 VGPRs (B-frags); bf16->f16
//     intermediates (more mantissa, same bytes).

#define SHIFT 9            // nodes per bucket = 512
#define EPB 4096           // edges per k_bucket block
#define HEPB 8192          // edges per k_bhist block
#define CAP 15104          // fill2 LDS srcs capacity (avg bucket = 8192)

using f32x4 = __attribute__((ext_vector_type(4))) float;
using f16x8 = __attribute__((ext_vector_type(8))) _Float16;
using f16x2 = __attribute__((ext_vector_type(2))) _Float16;

// Block-wide (256 thr) exclusive scan of one int per thread.
__device__ inline int scan256(int v, int* wsum) {
    __syncthreads();  // protect wsum reuse across calls
    int lane = threadIdx.x & 63, wid = threadIdx.x >> 6;
    int s = v;
#pragma unroll
    for (int d = 1; d < 64; d <<= 1) {
        int u = __shfl_up(s, d, 64);
        if (lane >= d) s += u;
    }
    if (lane == 63) wsum[wid] = s;
    __syncthreads();
    int off = 0;
    for (int w = 0; w < wid; w++) off += wsum[w];
    return off + s - v;
}

// Per-block LDS histogram of bucket ids -> global bucket histogram.
__global__ __launch_bounds__(256) void k_bhist(const int* __restrict__ coli,
                                               int* __restrict__ gbh,
                                               int E, int NB) {
    __shared__ int lh[256];
    int t = threadIdx.x;
    lh[t] = 0;
    __syncthreads();
    int base = blockIdx.x * HEPB;
    for (int i = t; i < HEPB; i += 256) {
        int e = base + i;
        if (e < E) atomicAdd(&lh[coli[e] >> SHIFT], 1);
    }
    __syncthreads();
    if (t < NB && lh[t]) atomicAdd(&gbh[t], lh[t]);
}

// One block: scan bucket sums -> bucketptr + cursors; rowptr[N]=E.
__global__ __launch_bounds__(256) void k_bscan(const int* __restrict__ gbh,
                                               int* __restrict__ bptr,
                                               int* __restrict__ bcur,
                                               int NB, int E,
                                               int* __restrict__ rowptr, int N) {
    __shared__ int wsum[4];
    int t = threadIdx.x;
    int v = (t < NB) ? gbh[t] : 0;
    int e = scan256(v, wsum);
    if (t < NB) { bptr[t] = e; bcur[t] = e; }
    if (t == 0) { bptr[NB] = E; rowptr[N] = E; }
}

// Bin EPB edges into LDS by bucket, burst-write (row,col) records to
// contiguous per-bucket runs (one global atomic per bucket per block).
__global__ __launch_bounds__(256) void k_bucket(const int* __restrict__ rowi,
                                                const int* __restrict__ coli,
                                                int* __restrict__ bcur,
                                                int2* __restrict__ recs,
                                                int E, int NB) {
    __shared__ int lh[256], excl[256], lcur[256], gbase[256], wsum[4];
    __shared__ int2 stage[EPB];
    int t = threadIdx.x;
    lh[t] = 0;
    __syncthreads();
    int base = blockIdx.x * EPB;
    int nE = min(EPB, E - base);
    int2 my[16];
    int cnt = 0;
#pragma unroll
    for (int i = 0; i < 16; i++) {
        int idx = t + i * 256;
        if (idx < nE) {
            my[cnt].x = rowi[base + idx];
            my[cnt].y = coli[base + idx];
            atomicAdd(&lh[my[cnt].y >> SHIFT], 1);
            cnt++;
        }
    }
    __syncthreads();
    int myh = lh[t];
    int ex = scan256(myh, wsum);
    excl[t] = ex;
    lcur[t] = ex;
    if (t < NB && myh) gbase[t] = atomicAdd(&bcur[t], myh);
    __syncthreads();
    for (int i = 0; i < cnt; i++) {
        int p = atomicAdd(&lcur[my[i].y >> SHIFT], 1);
        stage[p] = my[i];
    }
    __syncthreads();
    for (int i = t; i < nE; i += 256) {
        int2 r = stage[i];
        int bb = r.y >> SHIFT;
        recs[gbase[bb] + (i - excl[bb])] = r;
    }
}

// One block per bucket: local histogram -> rowptr/dis, LDS scatter of rows,
// coalesced burst write of srcs.
__global__ __launch_bounds__(256) void k_fill2(const int2* __restrict__ recs,
                                               const int* __restrict__ bptr,
                                               int* __restrict__ rowptr,
                                               float* __restrict__ dis,
                                               int* __restrict__ srcs, int N) {
    __shared__ int hist[512], excl[512], wsum[4];
    __shared__ int srcsL[CAP];
    int t = threadIdx.x;
    int b = blockIdx.x;
    int nbase = b << SHIFT;
    int start = bptr[b], end = bptr[b + 1];
    int cnt = end - start;
    hist[t] = 0;
    hist[t + 256] = 0;
    __syncthreads();
    for (int i = start + t; i < end; i += 256)
        atomicAdd(&hist[recs[i].y - nbase], 1);
    __syncthreads();
    int h0 = hist[2 * t], h1 = hist[2 * t + 1];
    int e0 = scan256(h0 + h1, wsum);
    excl[2 * t] = e0;
    excl[2 * t + 1] = e0 + h0;
    int n0 = nbase + 2 * t, n1 = nbase + 2 * t + 1;
    if (n0 < N) { rowptr[n0] = start + e0;      dis[n0] = rsqrtf((float)(h0 + 1)); }
    if (n1 < N) { rowptr[n1] = start + e0 + h0; dis[n1] = rsqrtf((float)(h1 + 1)); }
    __syncthreads();
    if (cnt <= CAP) {
        for (int i = start + t; i < end; i += 256) {
            int2 r = recs[i];
            int p = atomicAdd(&excl[r.y - nbase], 1);
            srcsL[p] = r.x;
        }
        __syncthreads();
        for (int i = t; i < cnt; i += 256) srcs[start + i] = srcsL[i];
    } else {  // pathological bucket: direct scatter (correct, slow)
        for (int i = start + t; i < end; i += 256) {
            int2 r = recs[i];
            int p = atomicAdd(&excl[r.y - nbase], 1);
            srcs[start + p] = r.x;
        }
    }
}

// Y[M,128] = dis[row] * (X[M,128] @ W[128,128]) -> f16, via MFMA 16x16x32.
// W cols [0,split) from Wa (f32, row stride split), [split,128) from Wb.
// W is converted to f16 and staged into LDS pre-swizzled in B-fragment order
// (frag (t,c): elem (lane,j) at ((t*4+c)*64+lane)*8+j), then hoisted into
// 32 f16x8 VGPR frags. Verified layouts (learn_hip m89/m120):
//   A[m=lane&15][k=quad*8+j], B[k=quad*8+j][n=lane&15],
//   C/D col=lane&15 row=quad*4+reg.
// Block = 4 waves x 16 rows = 64 rows/group; grid-stride over groups.
template <bool XF16>
__global__ __launch_bounds__(256) void k_gemm(const void* __restrict__ Xv,
                                              const float* __restrict__ Wa,
                                              const float* __restrict__ Wb,
                                              int split,
                                              const float* __restrict__ dis,
                                              _Float16* __restrict__ Y,
                                              int M, int ngroups) {
    __shared__ _Float16 Wl[16384];  // 32 KB swizzled
    int tid = threadIdx.x;
    int wbs = 128 - split;
    for (int i = tid; i < 16384; i += 256) {
        int k = i >> 7, n = i & 127;
        float v = (n < split) ? Wa[k * split + n] : Wb[k * wbs + (n - split)];
        int tt = n >> 4, c = (k >> 5), q = (k >> 3) & 3, ln = q * 16 + (n & 15);
        Wl[(((tt * 4 + c) * 64) + ln) * 8 + (k & 7)] = (_Float16)v;
    }
    __syncthreads();

    int lane = tid & 63, w = tid >> 6;
    f16x8 B[32];
#pragma unroll
    for (int i = 0; i < 32; i++)
        B[i] = *(const f16x8*)&Wl[(i * 64 + lane) * 8];

    int m16 = lane & 15, quad = lane >> 4;
    for (int g = blockIdx.x; g < ngroups; g += gridDim.x) {
        int rowbase = g * 64 + w * 16;
        if (rowbase >= M) continue;
        int arow = min(rowbase + m16, M - 1);
        f16x8 A[4];
        if (XF16) {
            const _Float16* X = (const _Float16*)Xv;
#pragma unroll
            for (int c = 0; c < 4; c++)
                A[c] = *(const f16x8*)&X[arow * 128 + c * 32 + quad * 8];
        } else {
            const float* X = (const float*)Xv;
#pragma unroll
            for (int c = 0; c < 4; c++) {
                float4 u0 = *(const float4*)&X[arow * 128 + c * 32 + quad * 8];
                float4 u1 = *(const float4*)&X[arow * 128 + c * 32 + quad * 8 + 4];
                f16x8 a;
                a[0] = (_Float16)u0.x; a[1] = (_Float16)u0.y;
                a[2] = (_Float16)u0.z; a[3] = (_Float16)u0.w;
                a[4] = (_Float16)u1.x; a[5] = (_Float16)u1.y;
                a[6] = (_Float16)u1.z; a[7] = (_Float16)u1.w;
                A[c] = a;
            }
        }

        f32x4 acc[8];
#pragma unroll
        for (int t = 0; t < 8; t++) acc[t] = (f32x4)(0.f);
#pragma unroll
        for (int t = 0; t < 8; t++)
#pragma unroll
            for (int c = 0; c < 4; c++)
                acc[t] = __builtin_amdgcn_mfma_f32_16x16x32_f16(
                    A[c], B[t * 4 + c], acc[t], 0, 0, 0);

#pragma unroll
        for (int r = 0; r < 4; r++) {
            int row = rowbase + quad * 4 + r;
            if (row < M) {
                float d = dis[row];
#pragma unroll
                for (int t = 0; t < 8; t++)
                    Y[row * 128 + t * 16 + m16] = (_Float16)(d * acc[t][r]);
            }
        }
    }
}

// F is dis-prescaled f16 [N,128]. out[i] = bias + dis_i * (F[i] + sum F[src]).
// One wave per node, 2 cols per lane, edge loop unrolled x4.
// OF16: output f16 (row stride 128, relu); else f32 split into outA/outB (64).
template <bool OF16>
__global__ __launch_bounds__(256) void k_agg(const f16x2* __restrict__ F,
                                             const float* __restrict__ dis,
                                             const int* __restrict__ rowptr,
                                             const int* __restrict__ srcs,
                                             const float* __restrict__ ba,
                                             const float* __restrict__ bb,
                                             void* __restrict__ outA,
                                             void* __restrict__ outB,
                                             int N) {
    int node = blockIdx.x * 4 + (threadIdx.x >> 6);
    if (node >= N) return;
    int lane = threadIdx.x & 63;
    f16x2 sv = F[node * 64 + lane];
    float ax = (float)sv[0];  // self term: F'[i] = dis_i * feat_i
    float ay = (float)sv[1];
    int s = rowptr[node], e = rowptr[node + 1];
    int t = s;
    for (; t + 4 <= e; t += 4) {
        int i0 = srcs[t + 0], i1 = srcs[t + 1];
        int i2 = srcs[t + 2], i3 = srcs[t + 3];
        f16x2 f0 = F[i0 * 64 + lane];
        f16x2 f1 = F[i1 * 64 + lane];
        f16x2 f2 = F[i2 * 64 + lane];
        f16x2 f3 = F[i3 * 64 + lane];
        ax += (float)f0[0] + (float)f1[0] + (float)f2[0] + (float)f3[0];
        ay += (float)f0[1] + (float)f1[1] + (float)f2[1] + (float)f3[1];
    }
    for (; t < e; t++) {
        int sr = srcs[t];
        f16x2 f = F[sr * 64 + lane];
        ax += (float)f[0];
        ay += (float)f[1];
    }
    float di = dis[node];
    int j = lane << 1;
    if (OF16) {
        float o0 = fmaxf(fmaf(di, ax, ba[j]), 0.f);
        float o1 = fmaxf(fmaf(di, ay, ba[j + 1]), 0.f);
        f16x2 o;
        o[0] = (_Float16)o0;
        o[1] = (_Float16)o1;
        ((f16x2*)outA)[node * 64 + lane] = o;
    } else {
        float* op;
        int jj;
        const float* bp;
        if (j < 64) { op = (float*)outA; jj = j; bp = ba; }
        else        { op = (float*)outB; jj = j - 64; bp = bb; }
        float o0 = fmaf(di, ax, bp[jj]);
        float o1 = fmaf(di, ay, bp[jj + 1]);
        *(float2*)&op[node * 64 + jj] = make_float2(o0, o1);
    }
}

__global__ __launch_bounds__(256) void k_final(const float* __restrict__ mu,
                                               const float* __restrict__ lv,
                                               const float* __restrict__ eps,
                                               float* __restrict__ z, int n) {
    int i = blockIdx.x * 256 + threadIdx.x;
    if (i < n) z[i] = fmaf(eps[i], expf(0.5f * lv[i]), mu[i]);
}

extern "C" void kernel_launch(void* const* d_in, const int* in_sizes, int n_in,
                              void* d_out, int out_size, void* d_ws, size_t ws_size,
                              hipStream_t stream) {
    const float* x   = (const float*)d_in[0];
    const int*   ei  = (const int*)d_in[1];
    const float* W1  = (const float*)d_in[2];
    const float* b1  = (const float*)d_in[3];
    const float* Wmu = (const float*)d_in[4];
    const float* bmu = (const float*)d_in[5];
    const float* Wlv = (const float*)d_in[6];
    const float* blv = (const float*)d_in[7];
    const float* eps = (const float*)d_in[8];

    int N = in_sizes[0] / 128;   // 100000
    int E = in_sizes[1] / 2;     // 1600000
    const int* rowi = ei;        // edge_index[0]
    const int* coli = ei + E;    // edge_index[1]
    int NB = (N + (1 << SHIFT) - 1) >> SHIFT;   // 196 buckets

    char* ws = (char*)d_ws;
    size_t off = 0;
    auto alloc = [&](size_t bytes) -> void* {
        void* p = ws + off;
        off += (bytes + 255) & ~(size_t)255;
        return p;
    };
    _Float16* bufA = (_Float16*)alloc((size_t)N * 128 * 2);  // F'1, F'2
    _Float16* bufB = (_Float16*)alloc((size_t)N * 128 * 2);  // h (f16)
    float* dis    = (float*)alloc((size_t)N * 4);
    int*   rowptr = (int*)alloc((size_t)(N + 1) * 4);
    int*   srcs   = (int*)alloc((size_t)E * 4);
    int2*  recs   = (int2*)alloc((size_t)E * 8);
    int*   bhist  = (int*)alloc((size_t)NB * 4);
    int*   bptr   = (int*)alloc((size_t)(NB + 1) * 4);
    int*   bcur   = (int*)alloc((size_t)NB * 4);

    float* zo  = (float*)d_out;                 // [N,64]
    float* muo = zo + (size_t)N * 64;           // [N,64]
    float* lvo = zo + (size_t)N * 128;          // [N,64]

    hipMemsetAsync(bhist, 0, (size_t)NB * 4, stream);
    k_bhist<<<(E + HEPB - 1) / HEPB, 256, 0, stream>>>(coli, bhist, E, NB);
    k_bscan<<<1, 256, 0, stream>>>(bhist, bptr, bcur, NB, E, rowptr, N);
    k_bucket<<<(E + EPB - 1) / EPB, 256, 0, stream>>>(rowi, coli, bcur, recs, E, NB);
    k_fill2<<<NB, 256, 0, stream>>>(recs, bptr, rowptr, dis, srcs, N);

    int ngroups = (N + 63) / 64;
    int gblk = ngroups < 640 ? ngroups : 640;
    // F'1 = dis . (x @ W1)   (f16, MFMA)
    k_gemm<false><<<gblk, 256, 0, stream>>>(x, W1, W1, 128, dis, bufA, N, ngroups);
    // h = relu(dis . (F'1[i] + sum F'1[src]) + b1)   (f16)
    k_agg<true><<<(N + 3) / 4, 256, 0, stream>>>((const f16x2*)bufA, dis, rowptr,
                                                 srcs, b1, b1, bufB, bufB, N);
    // F'2 = dis . (h @ [Wmu|Wlv])   (f16, MFMA)
    k_gemm<true><<<gblk, 256, 0, stream>>>(bufB, Wmu, Wlv, 64, dis, bufA, N, ngroups);
    // mu/lv = dis . (F'2[i] + sum F'2[src]) + b   (f32, direct to d_out)
    k_agg<false><<<(N + 3) / 4, 256, 0, stream>>>((const f16x2*)bufA, dis, rowptr,
                                                  srcs, bmu, blv, muo, lvo, N);
    k_final<<<((N * 64) + 255) / 256, 256, 0, stream>>>(muo, lvo, eps, zo, N * 64);
}